// Round 9
// baseline (127.215 us; speedup 1.0000x reference)
//
#include <hip/hip_runtime.h>
#include <math.h>

// Second-order IIR (B=1024 rows, T=16384), fp32.
// V10: 8-segment software pipeline (T3/T4: counted vmcnt, never 0 in the
// loop). 3 LDS buffers; segment i+3's DMA issued mid-iteration i; per-iter
// exact s_waitcnt vmcnt(N) from in-order issue accounting:
//   prologue L0 L1 L2; iter i issues L(i+3) then S(i)  (L=2 gll16, S=2 st)
//   N(i) = ops younger than L(i): 4,6,8,10,10,10,8,6.
// Minimal asm only (V7 lesson: no sched_barrier(0) spam): counted vmcnt at
// iter top + lgkmcnt(0)+s_barrier pairs. No big register state across
// barriers (V5 lesson): 2 float4 + 2 float2 per thread.
// Micro-chunk = 4 elems (V9-verified math): pass1 zero-state response from
// coalesced LDS slots, wave-0 scan per segment (A^4 folds, KS matrices
// loop-invariant, hoisted), pass3 recompute + coalesced register stores.

#define TLEN  16384
#define NT    256
#define NSEG  8
#define SEGF  2048                    // floats per segment
#define SEGS  512                     // float4 slots per segment
#define NBUF  3

__device__ __forceinline__ void gll16(const float4* g, float4* l) {
    __builtin_amdgcn_global_load_lds(
        (const __attribute__((address_space(1))) unsigned int*)g,
        (__attribute__((address_space(3))) unsigned int*)l,
        16, 0, 0);
}

__device__ __forceinline__ void mat2_sq(float& m00, float& m01, float& m10, float& m11) {
    float t00 = m00*m00 + m01*m10;
    float t01 = m00*m01 + m01*m11;
    float t10 = m10*m00 + m11*m10;
    float t11 = m10*m01 + m11*m11;
    m00 = t00; m01 = t01; m10 = t10; m11 = t11;
}

template<int VN> __device__ __forceinline__ void wait_vm() {
    asm volatile("s_waitcnt vmcnt(%0)" :: "n"(VN) : "memory");
}
__device__ __forceinline__ void bar_lgkm() {
    asm volatile("s_waitcnt lgkmcnt(0)" ::: "memory");
    __builtin_amdgcn_s_barrier();
}

struct Coef {
    float a1, a2, b0, b1, b2;
    float q00, q01, q10, q11;          // Q = A^4
    float k[6][4];                     // K[p] = Q^(8*2^p) = A^(32*2^p)
};

// One pipeline iteration for segment I.
template<int I, int N, bool DOSTAGE>
__device__ __forceinline__ void iter_seg(
    const Coef& c, int tid,
    const float4* up4, float4* op4,
    float4 (*buf)[SEGS], float2* st, float* stash, float* carry,
    float2 ui, float2 yi)
{
    wait_vm<N>();                                 // seg-I loads landed (this wave)
    __builtin_amdgcn_s_barrier();                 // all waves' loads landed

    const float4* bv = buf[I % NBUF];
    const float*  bf = (const float*)bv;

    // ---- pass 1: zero-state micro responses (micros m0=tid, m1=256+tid) ----
    float4 u40 = bv[tid];
    float4 u41 = bv[256 + tid];
    float2 h0, h1;
    h1 = *(const float2*)(bf + 4*(256 + tid) - 2);        // u[4m1-2], u[4m1-1]
    if (tid == 0) {
        if (I == 0) h0 = make_float2(ui.y, ui.x);          // (u_-2, u_-1)
        else        h0 = *(const float2*)&stash[2*(I & 1)];
    } else {
        h0 = *(const float2*)(bf + 4*tid - 2);
    }

    #define MICRO(U, H, D0, D1) {                                     \
        float va = fmaf(c.b2, (H).x, fmaf(c.b1, (H).y, c.b0*(U).x));  \
        float ya = va;                                                \
        float vb = fmaf(c.b2, (H).y, fmaf(c.b1, (U).x, c.b0*(U).y));  \
        float yb = fmaf(-c.a1, ya, vb);                               \
        float vc = fmaf(c.b2, (U).x, fmaf(c.b1, (U).y, c.b0*(U).z));  \
        float yc = fmaf(-c.a1, yb, fmaf(-c.a2, ya, vc));              \
        float vd = fmaf(c.b2, (U).y, fmaf(c.b1, (U).z, c.b0*(U).w));  \
        float yd = fmaf(-c.a1, yc, fmaf(-c.a2, yb, vd));              \
        (D0) = yd; (D1) = yc; }
    {
        float d0, d1;
        MICRO(u40, h0, d0, d1);  st[tid]       = make_float2(d0, d1);
        MICRO(u41, h1, d0, d1);  st[256 + tid] = make_float2(d0, d1);
    }
    #undef MICRO
    if (tid == NT - 1)                            // u tail -> next seg's m0 hist
        *(float2*)&stash[2*((I + 1) & 1)] = make_float2(u41.z, u41.w);

    bar_lgkm();                                   // states + stash visible; buf free

    if (DOSTAGE) {                                // refill this buffer for seg I+3
        gll16(up4 + (I + 3)*SEGS + tid,       buf[I % NBUF] + tid);
        gll16(up4 + (I + 3)*SEGS + 256 + tid, buf[I % NBUF] + 256 + tid);
    }

    // ---- wave-0 affine scan over 512 microstates ----
    if (tid < 64) {
        const int l = tid;
        float da[8], db[8];
        #pragma unroll
        for (int j = 0; j < 8; ++j) { float2 d = st[8*l + j]; da[j] = d.x; db[j] = d.y; }

        float seed0 = 0.0f, seed1 = 0.0f;
        if (l == 0) {
            if (I == 0) { seed0 = yi.x; seed1 = yi.y; }
            else        { seed0 = carry[0]; seed1 = carry[1]; }
        }
        float s0 = seed0, s1 = seed1;             // seeded fold of 8 micros (Q steps)
        #pragma unroll
        for (int m = 0; m < 8; ++m) {
            float n0 = fmaf(c.q00, s0, fmaf(c.q01, s1, da[m]));
            float n1 = fmaf(c.q10, s0, fmaf(c.q11, s1, db[m]));
            s0 = n0; s1 = n1;
        }
        #pragma unroll
        for (int p = 0; p < 6; ++p) {             // Kogge-Stone, precomputed K[p]
            float o0 = __shfl_up(s0, 1 << p);
            float o1 = __shfl_up(s1, 1 << p);
            if (l >= (1 << p)) {
                s0 = fmaf(c.k[p][0], o0, fmaf(c.k[p][1], o1, s0));
                s1 = fmaf(c.k[p][2], o0, fmaf(c.k[p][3], o1, s1));
            }
        }
        float p0 = __shfl_up(s0, 1);              // incoming for lane's first micro
        float p1 = __shfl_up(s1, 1);
        if (l == 0) { p0 = seed0; p1 = seed1; }
        float c0 = p0, c1 = p1;
        #pragma unroll
        for (int m = 0; m < 8; ++m) {             // down-sweep: incoming per micro
            st[8*l + m] = make_float2(c0, c1);
            float n0 = fmaf(c.q00, c0, fmaf(c.q01, c1, da[m]));
            float n1 = fmaf(c.q10, c0, fmaf(c.q11, c1, db[m]));
            c0 = n0; c1 = n1;
        }
        if (l == 63) { carry[0] = c0; carry[1] = c1; }   // end-of-seg state
    }
    bar_lgkm();                                   // prefixes visible

    // ---- pass 3: recompute with incoming state, coalesced register stores ----
    #define FIXUP(U, H, P, OUTIDX) {                                  \
        float va = fmaf(c.b2, (H).x, fmaf(c.b1, (H).y, c.b0*(U).x));  \
        float ya = fmaf(-c.a1, (P).x, fmaf(-c.a2, (P).y, va));        \
        float vb = fmaf(c.b2, (H).y, fmaf(c.b1, (U).x, c.b0*(U).y));  \
        float yb = fmaf(-c.a1, ya,   fmaf(-c.a2, (P).x, vb));         \
        float vc = fmaf(c.b2, (U).x, fmaf(c.b1, (U).y, c.b0*(U).z));  \
        float yc = fmaf(-c.a1, yb,   fmaf(-c.a2, ya,  vc));           \
        float vd = fmaf(c.b2, (U).y, fmaf(c.b1, (U).z, c.b0*(U).w));  \
        float yd = fmaf(-c.a1, yc,   fmaf(-c.a2, yb,  vd));           \
        float4 w; w.x = ya; w.y = yb; w.z = yc; w.w = yd;             \
        op4[OUTIDX] = w; }
    {
        float2 p0v = st[tid];
        float2 p1v = st[256 + tid];
        FIXUP(u40, h0, p0v, I*SEGS + tid);
        FIXUP(u41, h1, p1v, I*SEGS + 256 + tid);
    }
    #undef FIXUP
}

__global__ __launch_bounds__(NT, 5)
void iir_kernel(const float* __restrict__ bc,
                const float* __restrict__ rho_p,
                const float* __restrict__ psi_p,
                const float* __restrict__ u_in,
                const float* __restrict__ y_init,
                const float* __restrict__ u_init,
                float* __restrict__ y_out)
{
    __shared__ float4 buf[NBUF][SEGS];            // 24 KB staging (3 segments)
    __shared__ float2 st[512];                    // 4 KB micro states/prefixes
    __shared__ float  stash[4];                   // u-tail (2 slots, alternating)
    __shared__ float  carry[2];                   // y carry between segments

    const int row = blockIdx.x;
    const int tid = threadIdx.x;

    const float*  urow = u_in  + (size_t)row * TLEN;
    const float4* up4  = (const float4*)urow;
    float4*       op4  = (float4*)(y_out + (size_t)row * TLEN);

    // ---- prologue: stage segments 0,1,2 ----
    #pragma unroll
    for (int s = 0; s < 3; ++s) {
        gll16(up4 + s*SEGS + tid,       buf[s] + tid);
        gll16(up4 + s*SEGS + 256 + tid, buf[s] + 256 + tid);
    }

    // ---- scalar params + loop-invariant scan matrices (overlap DMA) ----
    float2 ui = *(const float2*)&u_init[2*row];   // (u_init[:,0], u_init[:,1])
    float2 yi = *(const float2*)&y_init[2*row];   // (y_-1, y_-2)
    Coef c;
    {
        const float rho = rho_p[0];
        const float psi = psi_p[0];
        const float r   = 1.0f / (1.0f + expf(-rho));
        const float th  = 3.14159265358979323846f / (1.0f + expf(-psi));
        c.a1 = -2.0f * r * cosf(th);
        c.a2 = r * r;
        c.b0 = bc[0]; c.b1 = bc[1]; c.b2 = bc[2];
        float m00 = -c.a1, m01 = -c.a2, m10 = 1.0f, m11 = 0.0f;   // A
        mat2_sq(m00, m01, m10, m11);
        mat2_sq(m00, m01, m10, m11);                              // Q = A^4
        c.q00 = m00; c.q01 = m01; c.q10 = m10; c.q11 = m11;
        mat2_sq(m00, m01, m10, m11);
        mat2_sq(m00, m01, m10, m11);
        mat2_sq(m00, m01, m10, m11);                              // A^32
        #pragma unroll
        for (int p = 0; p < 6; ++p) {
            c.k[p][0] = m00; c.k[p][1] = m01; c.k[p][2] = m10; c.k[p][3] = m11;
            if (p < 5) mat2_sq(m00, m01, m10, m11);
        }
    }

    // ---- pipelined segments; N from in-order vmcnt issue accounting ----
    iter_seg<0, 4,  true >(c, tid, up4, op4, buf, st, stash, carry, ui, yi);
    iter_seg<1, 6,  true >(c, tid, up4, op4, buf, st, stash, carry, ui, yi);
    iter_seg<2, 8,  true >(c, tid, up4, op4, buf, st, stash, carry, ui, yi);
    iter_seg<3, 10, true >(c, tid, up4, op4, buf, st, stash, carry, ui, yi);
    iter_seg<4, 10, true >(c, tid, up4, op4, buf, st, stash, carry, ui, yi);
    iter_seg<5, 10, false>(c, tid, up4, op4, buf, st, stash, carry, ui, yi);
    iter_seg<6, 8,  false>(c, tid, up4, op4, buf, st, stash, carry, ui, yi);
    iter_seg<7, 6,  false>(c, tid, up4, op4, buf, st, stash, carry, ui, yi);
}

extern "C" void kernel_launch(void* const* d_in, const int* in_sizes, int n_in,
                              void* d_out, int out_size, void* d_ws, size_t ws_size,
                              hipStream_t stream) {
    const float* bc    = (const float*)d_in[0];
    const float* rho   = (const float*)d_in[1];
    const float* psi   = (const float*)d_in[2];
    const float* u_in  = (const float*)d_in[3];
    const float* y_in  = (const float*)d_in[4];
    const float* u_ini = (const float*)d_in[5];
    float* y = (float*)d_out;
    const int B = in_sizes[3] / TLEN;     // 1024
    iir_kernel<<<B, NT, 0, stream>>>(bc, rho, psi, u_in, y_in, u_ini, y);
}